// Round 12
// baseline (354.395 us; speedup 1.0000x reference)
//
#include <hip/hip_runtime.h>

#define D 64
#define WQ_BITS 15
#define WQ_MAX 32767.0f
#define SHB 7              // 128-node shards
#define ROWS 128
#define MAXSH 1024         // N <= 131072 -> NSH <= 1024
#define CPAD 16            // counter padding: 16 ints = 64 B per counter line /4

typedef int      int4v   __attribute__((ext_vector_type(4)));
typedef float    float4v __attribute__((ext_vector_type(4)));
typedef unsigned uint2v  __attribute__((ext_vector_type(2)));

__device__ __forceinline__ ushort f2bf(float x) {
    unsigned u = __float_as_uint(x);
    unsigned r = (u + 0x7fff + ((u >> 16) & 1)) >> 16;  // round-to-nearest-even
    return (ushort)r;
}
__device__ __forceinline__ float bf2f(ushort u) {
    return __uint_as_float(((unsigned)u) << 16);
}

// ---------------------------------------------------------------------------
// P0: per-shard histogram. LDS hist (1 LDS atomic/edge), then one PADDED
// global atomic per (block,shard). Round-11 lesson: 16 counters on ONE cache
// line serialized 131k atomics at its home L2 -> 79 us at 1.4% VALU. Padding
// to 16 B stride spreads contention ~200 atomics/line.
__global__ __launch_bounds__(256) void count_kernel(
    const int* __restrict__ dst, int* __restrict__ shardCntP, int E, int NSH)
{
    __shared__ int hist[MAXSH];
    for (int s = threadIdx.x; s < MAXSH; s += 256) hist[s] = 0;
    __syncthreads();
    int stride = gridDim.x * 256;
    for (int e = blockIdx.x * 256 + threadIdx.x; e < E; e += stride) {
        int d = __builtin_nontemporal_load(&dst[e]);
        atomicAdd(&hist[d >> SHB], 1);
    }
    __syncthreads();
    for (int s = threadIdx.x; s < NSH; s += 256)
        if (hist[s] > 0) atomicAdd(&shardCntP[s * 4], hist[s]);  // 16 B stride
}

// ---------------------------------------------------------------------------
// Exclusive scan over NSH (<=1024) shard counts: one 1024-thread block.
__global__ __launch_bounds__(1024) void scan_kernel(
    const int* __restrict__ shardCntP, int* __restrict__ shardBase,
    int* __restrict__ shardCurP, int NSH)
{
    __shared__ int lds[1024];
    int t = threadIdx.x;
    int v = (t < NSH) ? shardCntP[t * 4] : 0;
    lds[t] = v;
    __syncthreads();
    for (int off = 1; off < 1024; off <<= 1) {
        int x = (t >= off) ? lds[t - off] : 0;
        __syncthreads();
        lds[t] += x;
        __syncthreads();
    }
    int ex = lds[t] - v;
    if (t < NSH) { shardBase[t] = ex; shardCurP[t * CPAD] = ex; }
    if (t == NSH - 1) shardBase[NSH] = ex + v;
}

// ---------------------------------------------------------------------------
// P1: exact placement. 256 blocks, each owns a contiguous edge chunk.
// Pass 1: local LDS hist. Reserve: ONE padded global atomic per (block,shard).
// Pass 2: place entries at exact offsets (LDS cursor). No capacity/overflow.
__global__ __launch_bounds__(256) void place_kernel(
    const int* __restrict__ src, const int* __restrict__ dst,
    const float* __restrict__ w, int* __restrict__ shardCurP,
    uint2* __restrict__ edgeBuf, int E, int NSH)
{
    __shared__ int lhist[MAXSH];
    __shared__ int lbase[MAXSH];
    int tid = threadIdx.x;
    int chunk = (E + gridDim.x - 1) / gridDim.x;
    int beg = blockIdx.x * chunk;
    int end = min(E, beg + chunk);

    for (int s = tid; s < MAXSH; s += 256) lhist[s] = 0;
    __syncthreads();
    for (int e = beg + tid; e < end; e += 256) {
        int d = __builtin_nontemporal_load(&dst[e]);
        atomicAdd(&lhist[d >> SHB], 1);
    }
    __syncthreads();
    for (int s = tid; s < NSH; s += 256) {
        int c = lhist[s];
        lbase[s] = (c > 0) ? atomicAdd(&shardCurP[s * CPAD], c) : 0;
        lhist[s] = 0;   // reuse as local cursor
    }
    __syncthreads();
    for (int e = beg + tid; e < end; e += 256) {
        int d    = __builtin_nontemporal_load(&dst[e]);
        int sv   = __builtin_nontemporal_load(&src[e]);
        float wr = __builtin_nontemporal_load(&w[e]);
        float wv = fminf(fmaxf(wr, 0.f), 1.f);
        unsigned wq = (unsigned)(wv * WQ_MAX + 0.5f);
        int s = d >> SHB;
        int pos = lbase[s] + atomicAdd(&lhist[s], 1);
        edgeBuf[pos] = make_uint2(((unsigned)sv << WQ_BITS) | wq, (unsigned)d);
    }
}

// ---------------------------------------------------------------------------
// Fused GEMM: out[n][j] = b[j] + sum_k h[n][k]*W[j][k]        (fp32)
//             g[n][j]   =        sum_k h[n][k]*W[j][64+k]     (bf16 store)
// 64 nodes/block, 4 nodes x 4 cols per thread, LDS-only inner reads,
// unroll 4 (round-2 lesson: full unroll -> 256 VGPR spill).
__global__ __launch_bounds__(256) void gemm_fused_kernel(
    const float* __restrict__ h, const float* __restrict__ W,
    const float* __restrict__ b, float* __restrict__ out,
    ushort* __restrict__ g, int N)
{
    __shared__ float Wt[128 * 64];  // Wt[k*64+j] = W[j*128+k]
    __shared__ float Xt[64 * 64];   // Xt[k*64+n] = h[(n0+n)*64+k]
    int tid = threadIdx.x;

    for (int idx = tid; idx < 128 * 64; idx += 256) {
        int j = idx & 63;
        int k = idx >> 6;
        Wt[k * 64 + j] = W[j * 128 + k];
    }

    int n0blk = blockIdx.x * 64;
    {
        int n = tid & 63;
        int krow = tid >> 6;  // 0..3
        int nn = min(n0blk + n, N - 1);
        #pragma unroll
        for (int c = 0; c < 4; ++c) {
            int k0 = (krow + c * 4) * 4;
            float4 v = *(const float4*)&h[(size_t)nn * D + k0];
            Xt[(k0 + 0) * 64 + n] = v.x;
            Xt[(k0 + 1) * 64 + n] = v.y;
            Xt[(k0 + 2) * 64 + n] = v.z;
            Xt[(k0 + 3) * 64 + n] = v.w;
        }
    }
    __syncthreads();

    int j0 = (tid & 15) * 4;
    int nb = (tid >> 4) * 4;

    float4 bv = *(const float4*)&b[j0];
    float accS[4][4], accG[4][4];
    #pragma unroll
    for (int i = 0; i < 4; ++i) {
        accS[i][0] = bv.x; accS[i][1] = bv.y; accS[i][2] = bv.z; accS[i][3] = bv.w;
        accG[i][0] = 0.f;  accG[i][1] = 0.f;  accG[i][2] = 0.f;  accG[i][3] = 0.f;
    }

    #pragma unroll 4
    for (int k = 0; k < 64; ++k) {
        float4 xv = *(const float4*)&Xt[k * 64 + nb];
        float4 w1 = *(const float4*)&Wt[k * 64 + j0];
        float4 w2 = *(const float4*)&Wt[(k + 64) * 64 + j0];
        #pragma unroll
        for (int i = 0; i < 4; ++i) {
            float x = (&xv.x)[i];
            accS[i][0] += x * w1.x; accS[i][1] += x * w1.y;
            accS[i][2] += x * w1.z; accS[i][3] += x * w1.w;
            accG[i][0] += x * w2.x; accG[i][1] += x * w2.y;
            accG[i][2] += x * w2.z; accG[i][3] += x * w2.w;
        }
    }

    #pragma unroll
    for (int i = 0; i < 4; ++i) {
        int n = n0blk + nb + i;
        if (n < N) {
            *(float4*)&out[(size_t)n * D + j0] =
                make_float4(accS[i][0], accS[i][1], accS[i][2], accS[i][3]);
            ushort4 gv;
            gv.x = f2bf(accG[i][0]); gv.y = f2bf(accG[i][1]);
            gv.z = f2bf(accG[i][2]); gv.w = f2bf(accG[i][3]);
            *(ushort4*)&g[(size_t)n * D + j0] = gv;
        }
    }
}

// ---------------------------------------------------------------------------
// P2: per-shard LDS aggregation. One block per 128-node shard (contiguous
// edge slice from the partition). 8 waves own 16 rows each -> plain
// ds_read+fma+ds_write, ZERO atomics (round-9 lesson: LDS fp32 atomics are
// ~10-20x slower than plain RMW). Per 64-edge batch: ballot owned edges,
// drain via MLP-8 shfl/gather queue.
__global__ __launch_bounds__(512) void shard_agg_kernel(
    const ushort* __restrict__ g, const uint2* __restrict__ edgeBuf,
    const int* __restrict__ shardBase, float* __restrict__ out, int N)
{
    __shared__ float acc[ROWS * 64];   // 32 KB
    int bin  = blockIdx.x;
    int tid  = threadIdx.x;
    int wave = tid >> 6;               // 0..7, owns rows [wave*16, wave*16+16)
    int lane = tid & 63;

    for (int i = tid; i < ROWS * 64; i += 512) acc[i] = 0.f;
    __syncthreads();

    int beg = shardBase[bin], end = shardBase[bin + 1];
    const float wscale = 1.0f / WQ_MAX;

    for (int base = beg; base < end; base += 64) {
        uint2 ev = make_uint2(0u, 0u);
        int idx = base + lane;
        if (idx < end) {
            uint2v t = __builtin_nontemporal_load((const uint2v*)&edgeBuf[idx]);
            ev = make_uint2(t[0], t[1]);
        }
        int row = (int)(ev.y & (ROWS - 1));
        bool valid = (idx < end) && ((row >> 4) == wave);
        unsigned long long mask = __ballot(valid);

        while (mask) {
            int js[8]; int m = 0;
            #pragma unroll
            for (int u = 0; u < 8; ++u) {
                if (mask) { js[u] = __ffsll(mask) - 1; mask &= mask - 1; m = u + 1; }
                else js[u] = 0;
            }
            unsigned cx[8], cy[8];
            #pragma unroll
            for (int u = 0; u < 8; ++u) {
                cx[u] = __shfl(ev.x, js[u]);
                cy[u] = __shfl(ev.y, js[u]);
            }
            float v[8];
            #pragma unroll
            for (int u = 0; u < 8; ++u)
                if (u < m)
                    v[u] = bf2f(g[(size_t)(cx[u] >> WQ_BITS) * D + lane]);
            #pragma unroll
            for (int u = 0; u < 8; ++u)
                if (u < m) {
                    int r = (int)(cy[u] & (ROWS - 1));
                    acc[r * 64 + lane] +=
                        (float)(cx[u] & 0x7fffu) * wscale * v[u];
                }
        }
    }
    __syncthreads();

    for (int r = wave; r < ROWS; r += 8) {
        int n = bin * ROWS + r;
        if (n < N)
            out[(size_t)n * D + lane] += acc[r * 64 + lane];
    }
}

// ---------------------------------------------------------------------------
// Fallback path (small ws / big N): round-1 kernels, known-good.
__global__ __launch_bounds__(256) void edge_scatter_kernel(
    const float* __restrict__ h, const float* __restrict__ w,
    const int* __restrict__ src, const int* __restrict__ dst,
    float* __restrict__ agg, int E)
{
    int e = blockIdx.x * 4 + (threadIdx.x >> 6);
    int lane = threadIdx.x & 63;
    if (e >= E) return;
    float val = w[e] * h[(size_t)src[e] * D + lane];
    atomicAdd(&agg[(size_t)dst[e] * D + lane], val);
}

__global__ __launch_bounds__(256) void out_linear_kernel(
    const float* __restrict__ h, const float* __restrict__ agg,
    const float* __restrict__ W, const float* __restrict__ b,
    float* __restrict__ out, int N)
{
    __shared__ float Wt[128 * 64];
    int lane = threadIdx.x & 63;
    int waveInBlock = threadIdx.x >> 6;
    int wavesPerBlock = blockDim.x >> 6;
    for (int idx = threadIdx.x; idx < 128 * 64; idx += blockDim.x) {
        int j = idx & 63;
        int k = idx >> 6;
        Wt[k * 64 + j] = W[j * 128 + k];
    }
    __syncthreads();
    float bj = b[lane];
    int wavesPerGrid = gridDim.x * wavesPerBlock;
    for (int n = blockIdx.x * wavesPerBlock + waveInBlock; n < N; n += wavesPerGrid) {
        float hreg = h[(size_t)n * D + lane];
        float areg = agg[(size_t)n * D + lane];
        float acc = bj;
        #pragma unroll
        for (int k = 0; k < 64; ++k) {
            float hk = __shfl(hreg, k, 64);
            float ak = __shfl(areg, k, 64);
            acc += hk * Wt[k * 64 + lane];
            acc += ak * Wt[(k + 64) * 64 + lane];
        }
        out[(size_t)n * D + lane] = acc;
    }
}

// ---------------------------------------------------------------------------
extern "C" void kernel_launch(void* const* d_in, const int* in_sizes, int n_in,
                              void* d_out, int out_size, void* d_ws, size_t ws_size,
                              hipStream_t stream) {
    const float* h   = (const float*)d_in[0];
    const float* w   = (const float*)d_in[1];
    const int*   src = (const int*)d_in[2];
    const int*   dst = (const int*)d_in[3];
    const float* W   = (const float*)d_in[4];
    const float* b   = (const float*)d_in[5];
    float* out = (float*)d_out;

    int N = in_sizes[0] / D;
    int E = in_sizes[1];
    int NSH = (N + ROWS - 1) >> SHB;

    auto align256 = [](size_t x) { return (x + 255) & ~(size_t)255; };
    size_t cntB  = align256((size_t)MAXSH * 4 * 4);       // shardCntP, 16 B stride
    size_t curB  = align256((size_t)MAXSH * CPAD * 4);    // shardCurP, 64 B stride
    size_t baseB = align256((size_t)(MAXSH + 1) * 4);
    size_t ebB   = align256((size_t)E * 8);               // 12.8 MB
    size_t gB    = align256((size_t)N * D * 2);           // 12.8 MB
    size_t need = cntB + curB + baseB + ebB + gB;

    if (ws_size >= need && N <= (1 << 17)) {
        char* p = (char*)d_ws;
        int*   shardCntP = (int*)p;   p += cntB;
        int*   shardCurP = (int*)p;   p += curB;
        int*   shardBase = (int*)p;   p += baseB;
        uint2* edgeBuf   = (uint2*)p; p += ebB;
        ushort* g        = (ushort*)p;

        hipMemsetAsync(shardCntP, 0, cntB, stream);

        count_kernel<<<256, 256, 0, stream>>>(dst, shardCntP, E, NSH);
        scan_kernel<<<1, 1024, 0, stream>>>(shardCntP, shardBase, shardCurP, NSH);
        place_kernel<<<256, 256, 0, stream>>>(src, dst, w, shardCurP,
                                              edgeBuf, E, NSH);
        gemm_fused_kernel<<<(N + 63) / 64, 256, 0, stream>>>(h, W, b, out, g, N);
        shard_agg_kernel<<<NSH, 512, 0, stream>>>(g, edgeBuf, shardBase, out, N);
    } else {
        float* agg = out;
        hipMemsetAsync(agg, 0, (size_t)N * D * 4, stream);
        edge_scatter_kernel<<<(E + 3) / 4, 256, 0, stream>>>(h, w, src, dst, agg, E);
        out_linear_kernel<<<2048, 256, 0, stream>>>(h, agg, W, b, out, N);
    }
}

// Round 13
// 259.158 us; speedup vs baseline: 1.3675x; 1.3675x over previous
//
#include <hip/hip_runtime.h>

#define D 64
#define CAP 32          // Poisson(16): P(deg>32) ~ 1e-4 -> ~10 overflow edges, handled
#define WQ_BITS 15
#define WQ_MAX 32767.0f
#define NSHARDS 8       // = XCD count; blockIdx%8 -> XCD round-robin heuristic

typedef int   int4v   __attribute__((ext_vector_type(4)));
typedef float float4v __attribute__((ext_vector_type(4)));

__device__ __forceinline__ ushort f2bf(float x) {
    unsigned u = __float_as_uint(x);
    unsigned r = (u + 0x7fff + ((u >> 16) & 1)) >> 16;  // round-to-nearest-even
    return (ushort)r;
}
__device__ __forceinline__ float bf2f(ushort u) {
    return __uint_as_float(((unsigned)u) << 16);
}

// ---------------------------------------------------------------------------
// XCD-sharded scatter (round-10 best, traffic-tuned). Round-10 PMC: 123 MB
// FETCH + 68 MB WRITE at 2.2 TB/s = the whole 88 us -> traffic-bound.
// Cut 1: dst loads CACHED (NT bypassed L3, so all 8 shard passes re-fetched
// dst from HBM = 51 MB; cached, L3 serves passes 2-8). src/w stay NT (they
// thrashed the pairs L2 window in round 5).
// Cut 2: CAP 32 halves the pairs region -> 1.6 MB write window per shard.
__global__ __launch_bounds__(256) void scatter_shard_kernel(
    const int* __restrict__ src, const int* __restrict__ dst,
    const float* __restrict__ w, int* __restrict__ cursor,
    unsigned* __restrict__ ovBits, unsigned* __restrict__ pairs,
    int E, int N)
{
    int shard   = blockIdx.x & (NSHARDS - 1);
    int slice   = blockIdx.x >> 3;
    int nSlices = gridDim.x >> 3;
    int n8 = (N + NSHARDS - 1) / NSHARDS;
    int lo = shard * n8;
    int hi = min(N, lo + n8);

    int e4 = E >> 2;  // full int4 groups
    for (int gi = slice * 256 + threadIdx.x; gi < e4; gi += nSlices * 256) {
        int e0 = gi * 4;
        int4v d4 = *(const int4v*)&dst[e0];   // cached: L3 serves re-passes
        #pragma unroll
        for (int i = 0; i < 4; ++i) {
            int d = d4[i];
            if (d >= lo && d < hi) {
                int e = e0 + i;
                int sv = __builtin_nontemporal_load(&src[e]);
                float wvr = __builtin_nontemporal_load(&w[e]);
                int pos = atomicAdd(&cursor[d], 1);
                if (pos < CAP) {
                    float wv = fminf(fmaxf(wvr, 0.f), 1.f);
                    unsigned wq = (unsigned)(wv * WQ_MAX + 0.5f);
                    pairs[(size_t)d * CAP + pos] =
                        ((unsigned)sv << WQ_BITS) | wq;
                } else {
                    atomicOr(&ovBits[e >> 5], 1u << (e & 31));
                }
            }
        }
    }
    // tail (E % 4 edges), filtered by the same shard predicate
    for (int e = e4 * 4 + slice * 256 + threadIdx.x; e < E; e += nSlices * 256) {
        int d = dst[e];
        if (d >= lo && d < hi) {
            int pos = atomicAdd(&cursor[d], 1);
            if (pos < CAP) {
                float wv = fminf(fmaxf(w[e], 0.f), 1.f);
                unsigned wq = (unsigned)(wv * WQ_MAX + 0.5f);
                pairs[(size_t)d * CAP + pos] =
                    ((unsigned)src[e] << WQ_BITS) | wq;
            } else {
                atomicOr(&ovBits[e >> 5], 1u << (e & 31));
            }
        }
    }
}

// ---------------------------------------------------------------------------
// Fused GEMM: out[n][j] = b[j] + sum_k h[n][k]*W[j][k]        (fp32)
//             g[n][j]   =        sum_k h[n][k]*W[j][64+k]     (bf16 store)
// 64 nodes/block, 4 nodes x 4 cols per thread, LDS-only inner reads,
// unroll 4 (round-2 lesson: full unroll -> 256 VGPR spill).
__global__ __launch_bounds__(256) void gemm_fused_kernel(
    const float* __restrict__ h, const float* __restrict__ W,
    const float* __restrict__ b, float* __restrict__ out,
    ushort* __restrict__ g, int N)
{
    __shared__ float Wt[128 * 64];  // Wt[k*64+j] = W[j*128+k]
    __shared__ float Xt[64 * 64];   // Xt[k*64+n] = h[(n0+n)*64+k]
    int tid = threadIdx.x;

    for (int idx = tid; idx < 128 * 64; idx += 256) {
        int j = idx & 63;
        int k = idx >> 6;
        Wt[k * 64 + j] = W[j * 128 + k];
    }

    int n0blk = blockIdx.x * 64;
    {
        int n = tid & 63;
        int krow = tid >> 6;  // 0..3
        int nn = min(n0blk + n, N - 1);
        #pragma unroll
        for (int c = 0; c < 4; ++c) {
            int k0 = (krow + c * 4) * 4;
            float4 v = *(const float4*)&h[(size_t)nn * D + k0];
            Xt[(k0 + 0) * 64 + n] = v.x;
            Xt[(k0 + 1) * 64 + n] = v.y;
            Xt[(k0 + 2) * 64 + n] = v.z;
            Xt[(k0 + 3) * 64 + n] = v.w;
        }
    }
    __syncthreads();

    int j0 = (tid & 15) * 4;
    int nb = (tid >> 4) * 4;

    float4 bv = *(const float4*)&b[j0];
    float accS[4][4], accG[4][4];
    #pragma unroll
    for (int i = 0; i < 4; ++i) {
        accS[i][0] = bv.x; accS[i][1] = bv.y; accS[i][2] = bv.z; accS[i][3] = bv.w;
        accG[i][0] = 0.f;  accG[i][1] = 0.f;  accG[i][2] = 0.f;  accG[i][3] = 0.f;
    }

    #pragma unroll 4
    for (int k = 0; k < 64; ++k) {
        float4 xv = *(const float4*)&Xt[k * 64 + nb];
        float4 w1 = *(const float4*)&Wt[k * 64 + j0];
        float4 w2 = *(const float4*)&Wt[(k + 64) * 64 + j0];
        #pragma unroll
        for (int i = 0; i < 4; ++i) {
            float x = (&xv.x)[i];
            accS[i][0] += x * w1.x; accS[i][1] += x * w1.y;
            accS[i][2] += x * w1.z; accS[i][3] += x * w1.w;
            accG[i][0] += x * w2.x; accG[i][1] += x * w2.y;
            accG[i][2] += x * w2.z; accG[i][3] += x * w2.w;
        }
    }

    #pragma unroll
    for (int i = 0; i < 4; ++i) {
        int n = n0blk + nb + i;
        if (n < N) {
            *(float4*)&out[(size_t)n * D + j0] =
                make_float4(accS[i][0], accS[i][1], accS[i][2], accS[i][3]);
            ushort4 gv;
            gv.x = f2bf(accG[i][0]); gv.y = f2bf(accG[i][1]);
            gv.z = f2bf(accG[i][2]); gv.w = f2bf(accG[i][3]);
            *(ushort4*)&g[(size_t)n * D + j0] = gv;
        }
    }
}

// ---------------------------------------------------------------------------
// Final: out[n] += sum over bucket(n) of w_e * g_bf16[src_e].
// One wave per node. CAP=32 codes arrive in one coalesced 128 B load
// (lane<32 side), broadcast via shfl; MLP-16 gather queue.
__global__ __launch_bounds__(256) void final_agg_kernel(
    const ushort* __restrict__ g, const unsigned* __restrict__ pairs,
    const int* __restrict__ cursor, float* __restrict__ out, int N)
{
    int wave = threadIdx.x >> 6;
    int lane = threadIdx.x & 63;
    int n = blockIdx.x * 4 + wave;
    if (n >= N) return;
    int cnt = min(cursor[n], CAP);
    unsigned mycode = (lane < CAP) ? pairs[(size_t)n * CAP + lane] : 0u;
    float acc = out[(size_t)n * D + lane];

    const float wscale = 1.0f / WQ_MAX;
    int j = 0;
    for (; j + 16 <= cnt; j += 16) {
        unsigned c[16];
        float v[16];
        #pragma unroll
        for (int u = 0; u < 16; ++u) c[u] = __shfl(mycode, j + u);
        #pragma unroll
        for (int u = 0; u < 16; ++u)
            v[u] = bf2f(g[(size_t)(c[u] >> WQ_BITS) * D + lane]);
        #pragma unroll
        for (int u = 0; u < 16; ++u)
            acc += (float)(c[u] & 0x7fffu) * wscale * v[u];
    }
    for (; j + 4 <= cnt; j += 4) {
        unsigned c[4];
        float v[4];
        #pragma unroll
        for (int u = 0; u < 4; ++u) c[u] = __shfl(mycode, j + u);
        #pragma unroll
        for (int u = 0; u < 4; ++u)
            v[u] = bf2f(g[(size_t)(c[u] >> WQ_BITS) * D + lane]);
        #pragma unroll
        for (int u = 0; u < 4; ++u)
            acc += (float)(c[u] & 0x7fffu) * wscale * v[u];
    }
    for (; j < cnt; ++j) {
        unsigned c = __shfl(mycode, j);
        acc += (float)(c & 0x7fffu) * wscale *
               bf2f(g[(size_t)(c >> WQ_BITS) * D + lane]);
    }
    out[(size_t)n * D + lane] = acc;
}

// ---------------------------------------------------------------------------
// Overflow cleanup (runs after final_agg; ~10 edges at CAP=32).
__global__ __launch_bounds__(256) void overflow_kernel(
    const unsigned* __restrict__ ovBits, const int* __restrict__ src,
    const int* __restrict__ dst, const float* __restrict__ w,
    const ushort* __restrict__ g, float* __restrict__ out, int numWords)
{
    int idx = blockIdx.x * 256 + threadIdx.x;
    for (int wi = idx; wi < numWords; wi += gridDim.x * 256) {
        unsigned bits = ovBits[wi];
        while (bits) {
            int bit = __ffs(bits) - 1;
            bits &= bits - 1;
            int e = wi * 32 + bit;
            int s = src[e], d = dst[e];
            float wv = w[e];
            for (int f = 0; f < D; ++f)
                atomicAdd(&out[(size_t)d * D + f], wv * bf2f(g[(size_t)s * D + f]));
        }
    }
}

// ---------------------------------------------------------------------------
// Fallback path (small ws / big N): round-1 kernels, known-good.
__global__ __launch_bounds__(256) void edge_scatter_kernel(
    const float* __restrict__ h, const float* __restrict__ w,
    const int* __restrict__ src, const int* __restrict__ dst,
    float* __restrict__ agg, int E)
{
    int e = blockIdx.x * 4 + (threadIdx.x >> 6);
    int lane = threadIdx.x & 63;
    if (e >= E) return;
    float val = w[e] * h[(size_t)src[e] * D + lane];
    atomicAdd(&agg[(size_t)dst[e] * D + lane], val);
}

__global__ __launch_bounds__(256) void out_linear_kernel(
    const float* __restrict__ h, const float* __restrict__ agg,
    const float* __restrict__ W, const float* __restrict__ b,
    float* __restrict__ out, int N)
{
    __shared__ float Wt[128 * 64];
    int lane = threadIdx.x & 63;
    int waveInBlock = threadIdx.x >> 6;
    int wavesPerBlock = blockDim.x >> 6;
    for (int idx = threadIdx.x; idx < 128 * 64; idx += blockDim.x) {
        int j = idx & 63;
        int k = idx >> 6;
        Wt[k * 64 + j] = W[j * 128 + k];
    }
    __syncthreads();
    float bj = b[lane];
    int wavesPerGrid = gridDim.x * wavesPerBlock;
    for (int n = blockIdx.x * wavesPerBlock + waveInBlock; n < N; n += wavesPerGrid) {
        float hreg = h[(size_t)n * D + lane];
        float areg = agg[(size_t)n * D + lane];
        float acc = bj;
        #pragma unroll
        for (int k = 0; k < 64; ++k) {
            float hk = __shfl(hreg, k, 64);
            float ak = __shfl(areg, k, 64);
            acc += hk * Wt[k * 64 + lane];
            acc += ak * Wt[(k + 64) * 64 + lane];
        }
        out[(size_t)n * D + lane] = acc;
    }
}

// ---------------------------------------------------------------------------
extern "C" void kernel_launch(void* const* d_in, const int* in_sizes, int n_in,
                              void* d_out, int out_size, void* d_ws, size_t ws_size,
                              hipStream_t stream) {
    const float* h   = (const float*)d_in[0];
    const float* w   = (const float*)d_in[1];
    const int*   src = (const int*)d_in[2];
    const int*   dst = (const int*)d_in[3];
    const float* W   = (const float*)d_in[4];
    const float* b   = (const float*)d_in[5];
    float* out = (float*)d_out;

    int N = in_sizes[0] / D;
    int E = in_sizes[1];
    int numWords = (E + 31) / 32;

    auto align256 = [](size_t x) { return (x + 255) & ~(size_t)255; };
    size_t cursorB = align256((size_t)N * 4);
    size_t ovB     = align256((size_t)numWords * 4);
    size_t pairsB  = align256((size_t)N * CAP * 4);   // 12.8 MB at CAP=32
    size_t gB      = align256((size_t)N * D * 2);
    size_t need = cursorB + ovB + pairsB + gB;

    if (ws_size >= need && N <= (1 << 17)) {
        char* p = (char*)d_ws;
        int*      cursor = (int*)p;       p += cursorB;
        unsigned* ovBits = (unsigned*)p;  p += ovB;
        unsigned* pairs  = (unsigned*)p;  p += pairsB;
        ushort*   g      = (ushort*)p;

        // cursor + ovBits are contiguous: one memset
        hipMemsetAsync(cursor, 0, cursorB + ovB, stream);

        scatter_shard_kernel<<<4096, 256, 0, stream>>>(src, dst, w, cursor,
                                                       ovBits, pairs, E, N);
        gemm_fused_kernel<<<(N + 63) / 64, 256, 0, stream>>>(h, W, b, out, g, N);
        final_agg_kernel<<<(N + 3) / 4, 256, 0, stream>>>(g, pairs, cursor, out, N);
        overflow_kernel<<<64, 256, 0, stream>>>(ovBits, src, dst, w, g, out, numWords);
    } else {
        float* agg = out;
        hipMemsetAsync(agg, 0, (size_t)N * D * 4, stream);
        edge_scatter_kernel<<<(E + 3) / 4, 256, 0, stream>>>(h, w, src, dst, agg, E);
        out_linear_kernel<<<2048, 256, 0, stream>>>(h, agg, W, b, out, N);
    }
}